// Round 1
// baseline (1986.406 us; speedup 1.0000x reference)
//
#include <hip/hip_runtime.h>

#define NN 16
#define CC 192
#define TT 120
#define VV 100
#define NH 4
#define HC 48

typedef __attribute__((ext_vector_type(4))) float  float4v;
typedef __attribute__((ext_vector_type(8))) short  short8;
typedef __attribute__((ext_vector_type(4))) short  short4v;

#define MFMA16(A,B,Cacc) __builtin_amdgcn_mfma_f32_16x16x32_bf16(A,B,Cacc,0,0,0)

__device__ __forceinline__ short f2b(float f) {
  union { float f; unsigned u; } x; x.f = f;
  unsigned r = x.u + 0x7fffu + ((x.u >> 16) & 1u);
  return (short)(r >> 16);
}

// ---------------- kernel 1: weight fp32 -> bf16 ----------------
__global__ __launch_bounds__(256) void k_conv(const float* __restrict__ wq,
                                              const float* __restrict__ wk,
                                              const float* __restrict__ wp,
                                              short* __restrict__ wqb,
                                              short* __restrict__ wkb,
                                              short* __restrict__ wpb) {
  int i = blockIdx.x * 256 + threadIdx.x;          // grid 576 -> 147456 threads
  if (i < CC*CC) { wqb[i] = f2b(wq[i]); wkb[i] = f2b(wk[i]); }
  if (i < CC*CC*NH) wpb[i] = f2b(wp[i]);
}

// ---------------- kernel 2: fused QK projection + scores ----------------
// grid 240 = (n, tc) ; 448 threads = 7 waves, wave w owns u-tile w (u = 16w..16w+15)
__global__ __launch_bounds__(448) void k_scores(const float* __restrict__ xq,
                                                const float* __restrict__ xkv,
                                                const short* __restrict__ wqb,
                                                const short* __restrict__ wkb,
                                                const float* __restrict__ bq,
                                                const float* __restrict__ bk,
                                                float* __restrict__ part) {
  __shared__ short Qt[112][72];   // [u][c], c 0..47 valid, 48..63 kept zero, stride 144B (16B aligned, 2-way banks)
  __shared__ short Kt[112][72];
  const int n = blockIdx.x / 15, tc = blockIdx.x % 15;
  const int tid = threadIdx.x, w = tid >> 6, lane = tid & 63;
  const int quad = lane >> 4, l15 = lane & 15;

  for (int i = tid; i < 112*72/2; i += 448) { ((int*)Qt)[i] = 0; ((int*)Kt)[i] = 0; }
  __syncthreads();

  float4v acc[NH][7];
  #pragma unroll
  for (int s = 0; s < NH; ++s)
    #pragma unroll
    for (int vt = 0; vt < 7; ++vt) acc[s][vt] = (float4v){0.f,0.f,0.f,0.f};

  const int u  = 16*w + l15;            // 0..111
  const int uc = (u < VV) ? u : (VV-1); // clamp for global reads

  for (int it = 0; it < 8; ++it) {
    const int t = tc*8 + it;
    // X fragments (B-operand: B[k=a][n=u]) for this wave's u-tile; shared across all heads
    short8 xqf[6], xkf[6];
    #pragma unroll
    for (int kc = 0; kc < 6; ++kc) {
      #pragma unroll
      for (int j = 0; j < 8; ++j) {
        int a = 32*kc + quad*8 + j;
        int idx = (n*CC + a)*TT*VV + t*VV + uc;
        xqf[kc][j] = f2b(xq[idx]);
        xkf[kc][j] = f2b(xkv[idx]);
      }
    }
    #pragma unroll
    for (int s = 0; s < NH; ++s) {
      // GEMM1: Qh[c][u] = wq_s @ xq  (A = wq rows, B = x frags)
      float4v dq[3], dk[3];
      #pragma unroll
      for (int ct = 0; ct < 3; ++ct) { dq[ct] = (float4v){0.f,0.f,0.f,0.f}; dk[ct] = (float4v){0.f,0.f,0.f,0.f}; }
      #pragma unroll
      for (int kc = 0; kc < 6; ++kc) {
        #pragma unroll
        for (int ct = 0; ct < 3; ++ct) {
          short8 aq = *(const short8*)&wqb[(HC*s + 16*ct + l15)*CC + 32*kc + quad*8];
          short8 ak = *(const short8*)&wkb[(HC*s + 16*ct + l15)*CC + 32*kc + quad*8];
          dq[ct] = MFMA16(aq, xqf[kc], dq[ct]);
          dk[ct] = MFMA16(ak, xkf[kc], dk[ct]);
        }
      }
      #pragma unroll
      for (int ct = 0; ct < 3; ++ct) {
        int c0 = 16*ct + quad*4;
        float4v bqv = *(const float4v*)&bq[HC*s + c0];
        float4v bkv = *(const float4v*)&bk[HC*s + c0];
        short4v pq, pk;
        #pragma unroll
        for (int r = 0; r < 4; ++r) { pq[r] = f2b(dq[ct][r] + bqv[r]); pk[r] = f2b(dk[ct][r] + bkv[r]); }
        *(short4v*)&Qt[u][c0] = pq;
        *(short4v*)&Kt[u][c0] = pk;
      }
      __syncthreads();
      // S[u][v] += Qt^ . Kt  (A = Qt rows, B = Kt rows; cols 48..63 are zero)
      short8 aS0 = *(const short8*)&Qt[u][quad*8];
      short8 aS1 = *(const short8*)&Qt[u][32 + quad*8];
      #pragma unroll
      for (int vt = 0; vt < 7; ++vt) {
        short8 b0 = *(const short8*)&Kt[16*vt + l15][quad*8];
        short8 b1 = *(const short8*)&Kt[16*vt + l15][32 + quad*8];
        acc[s][vt] = MFMA16(aS0, b0, acc[s][vt]);
        acc[s][vt] = MFMA16(aS1, b1, acc[s][vt]);
      }
      __syncthreads();
    }
  }
  // flush partial S: part[n][tc][s][v][u(112)], D: col=v=l15, row=u=quad*4+r
  const int u0 = 16*w + quad*4;
  #pragma unroll
  for (int s = 0; s < NH; ++s)
    #pragma unroll
    for (int vt = 0; vt < 7; ++vt) {
      int v = 16*vt + l15;
      if (v < VV)
        *(float4v*)&part[(((n*15 + tc)*NH + s)*VV + v)*112 + u0] = acc[s][vt];
    }
}

// ---------------- kernel 3: reduce + tanh + alpha/ga, store attnT bf16 ----------------
// grid 256 = (n, s, v-chunk of 28); attnT[n][s][v(112)][u(128)], zero outside 100x100
__global__ __launch_bounds__(256) void k_reduce(const float* __restrict__ part,
                                                const float* __restrict__ alphas,
                                                const float* __restrict__ ga,
                                                short* __restrict__ attnT) {
  int bid = blockIdx.x;
  int n = bid >> 4, s = (bid >> 2) & 3, vc = bid & 3;
  float alpha = alphas[s];
  for (int i = threadIdx.x; i < 28*128; i += 256) {
    int vl = i >> 7, uu = i & 127;
    int v = vc*28 + vl;
    float val = 0.f;
    if (v < VV && uu < VV) {
      float sum = 0.f;
      for (int tcc = 0; tcc < 15; ++tcc)
        sum += part[(((n*15 + tcc)*NH + s)*VV + v)*112 + uu];
      val = tanhf(sum * (1.f/5760.f)) * alpha + ga[uu*VV + v];
    }
    attnT[((n*NH + s)*112 + v)*128 + uu] = f2b(val);
  }
}

// ---------------- kernel 4: fused value-proj + attention-apply + out-proj ----------------
// grid 1920 = (n, t); 256 threads = 4 waves
__global__ __launch_bounds__(256) void k_out(const float* __restrict__ xkv,
                                             const short* __restrict__ wpb,
                                             const short* __restrict__ attnT,
                                             const float* __restrict__ bp,
                                             float* __restrict__ out) {
  __shared__ short Ms[CC][136];   // [o][u], u 0..99 valid, 100..135 zero; stride 272B (16B aligned)
  const int n = blockIdx.x / TT, t = blockIdx.x % TT;
  const int tid = threadIdx.x, w = tid >> 6, lane = tid & 63;
  const int quad = lane >> 4, l15 = lane & 15;

  for (int i = tid; i < CC*136/2; i += 256) ((int*)Ms)[i] = 0;

  // X A-fragments (A[m=u][k=a]); wave w owns u-tiles {w, w+4}; reused across heads
  short8 xf[2][6];
  #pragma unroll
  for (int ui = 0; ui < 2; ++ui) {
    int uu = 16*(w + 4*ui) + l15;
    int uc = (uu < VV) ? uu : (VV-1);
    #pragma unroll
    for (int kc = 0; kc < 6; ++kc)
      #pragma unroll
      for (int j = 0; j < 8; ++j) {
        int a = 32*kc + quad*8 + j;
        xf[ui][kc][j] = f2b(xkv[(n*CC + a)*TT*VV + t*VV + uc]);
      }
  }
  __syncthreads();   // Ms zeroing visible

  float4v acc[3][7];  // [oi][vt], o-tiles {w, w+4, w+8}
  #pragma unroll
  for (int oi = 0; oi < 3; ++oi)
    #pragma unroll
    for (int vt = 0; vt < 7; ++vt) acc[oi][vt] = (float4v){0.f,0.f,0.f,0.f};

  for (int s = 0; s < NH; ++s) {
    // B1: Ms[o][u] = sum_a wp[o][s*192+a] * xkv[a][u]
    #pragma unroll
    for (int ui = 0; ui < 2; ++ui) {
      int u0 = 16*(w + 4*ui) + quad*4;
      float4v d1[12];
      #pragma unroll
      for (int ot = 0; ot < 12; ++ot) d1[ot] = (float4v){0.f,0.f,0.f,0.f};
      #pragma unroll
      for (int kc = 0; kc < 6; ++kc)
        #pragma unroll
        for (int ot = 0; ot < 12; ++ot) {
          short8 bf = *(const short8*)&wpb[(16*ot + l15)*(CC*NH) + s*CC + 32*kc + quad*8];
          d1[ot] = MFMA16(xf[ui][kc], bf, d1[ot]);
        }
      #pragma unroll
      for (int ot = 0; ot < 12; ++ot) {
        short4v pv;
        #pragma unroll
        for (int r = 0; r < 4; ++r) pv[r] = (u0 < VV) ? f2b(d1[ot][r]) : (short)0;
        *(short4v*)&Ms[16*ot + l15][u0] = pv;
      }
    }
    __syncthreads();
    // B2: out[v][o] += attnT[v][u] * Ms[o][u]
    #pragma unroll
    for (int kc = 0; kc < 4; ++kc) {
      short8 af[7];
      #pragma unroll
      for (int vt = 0; vt < 7; ++vt)
        af[vt] = *(const short8*)&attnT[((n*NH + s)*112 + 16*vt + l15)*128 + 32*kc + quad*8];
      #pragma unroll
      for (int oi = 0; oi < 3; ++oi) {
        short8 bf = *(const short8*)&Ms[16*(w + 4*oi) + l15][32*kc + quad*8];
        #pragma unroll
        for (int vt = 0; vt < 7; ++vt)
          acc[oi][vt] = MFMA16(af[vt], bf, acc[oi][vt]);
      }
    }
    __syncthreads();
  }
  // epilogue: + bp, store; D: col=o=l15, row=v=quad*4+r
  #pragma unroll
  for (int oi = 0; oi < 3; ++oi) {
    int o = 16*(w + 4*oi) + l15;
    float bpv = bp[o];
    #pragma unroll
    for (int vt = 0; vt < 7; ++vt) {
      int v0 = 16*vt + quad*4;
      if (v0 < VV) {
        float4v r = acc[oi][vt];
        r[0] += bpv; r[1] += bpv; r[2] += bpv; r[3] += bpv;
        *(float4v*)&out[((n*CC + o)*TT + t)*VV + v0] = r;
      }
    }
  }
}

extern "C" void kernel_launch(void* const* d_in, const int* in_sizes, int n_in,
                              void* d_out, int out_size, void* d_ws, size_t ws_size,
                              hipStream_t stream) {
  const float* xq     = (const float*)d_in[0];
  const float* xkv    = (const float*)d_in[1];
  const float* wq     = (const float*)d_in[2];
  const float* bq     = (const float*)d_in[3];
  const float* wk     = (const float*)d_in[4];
  const float* bk     = (const float*)d_in[5];
  const float* wp     = (const float*)d_in[6];
  const float* bp     = (const float*)d_in[7];
  const float* alphas = (const float*)d_in[8];
  const float* ga     = (const float*)d_in[9];
  float* out = (float*)d_out;
  char*  ws  = (char*)d_ws;

  // ws layout (bytes): wqb 0..73728, wkb ..147456, wpb ..442368,
  // attnT ..2277376 (16*4*112*128 bf16), partials ..45285376 (16*15*4*100*112 f32)
  short* wqb   = (short*)(ws);
  short* wkb   = (short*)(ws + 73728);
  short* wpb   = (short*)(ws + 147456);
  short* attnT = (short*)(ws + 442368);
  float* part  = (float*)(ws + 2277376);

  hipLaunchKernelGGL(k_conv,   dim3(576),  dim3(256), 0, stream, wq, wk, wp, wqb, wkb, wpb);
  hipLaunchKernelGGL(k_scores, dim3(240),  dim3(448), 0, stream, xq, xkv, wqb, wkb, bq, bk, part);
  hipLaunchKernelGGL(k_reduce, dim3(256),  dim3(256), 0, stream, part, alphas, ga, attnT);
  hipLaunchKernelGGL(k_out,    dim3(1920), dim3(256), 0, stream, xkv, wpb, attnT, bp, out);
}

// Round 2
// 1433.513 us; speedup vs baseline: 1.3857x; 1.3857x over previous
//
#include <hip/hip_runtime.h>

#define NN 16
#define CC 192
#define TT 120
#define VV 100
#define NH 4

typedef __attribute__((ext_vector_type(4))) float  float4v;
typedef __attribute__((ext_vector_type(8))) short  short8;
typedef __attribute__((ext_vector_type(2))) int    int2v;

#define MFMA16(A,B,Cacc) __builtin_amdgcn_mfma_f32_16x16x32_bf16(A,B,Cacc,0,0,0)

union S8U { unsigned u[4]; short8 s; };

// truncating f32->bf16 pair pack: returns bf16(b)<<16 | bf16(a)  (1 v_perm)
__device__ __forceinline__ unsigned pk2(float a, float b) {
  union { float f; unsigned u; } x, y; x.f = a; y.f = b;
  return __builtin_amdgcn_perm(y.u, x.u, 0x07060302u);
}
__device__ __forceinline__ short b16t(float f) {
  union { float f; unsigned u; } x; x.f = f;
  return (short)(x.u >> 16);
}
// RNE (for one-time weight conversion)
__device__ __forceinline__ short f2b(float f) {
  union { float f; unsigned u; } x; x.f = f;
  unsigned r = x.u + 0x7fffu + ((x.u >> 16) & 1u);
  return (short)(r >> 16);
}

// ---------------- kernel 1: weights fp32 -> bf16, pre-swizzled into MFMA B-frag order ----------------
// frag layout: [tile][kc][lane(q*16+l15)][j]  <->  w[o=16*tile+l15][a=32*kc+8*q+j]
__global__ __launch_bounds__(256) void k_conv(const float* __restrict__ wq,
                                              const float* __restrict__ wk,
                                              const float* __restrict__ wp,
                                              short* __restrict__ wqF,
                                              short* __restrict__ wkF,
                                              short* __restrict__ wpF) {
  int i = blockIdx.x * 256 + threadIdx.x;   // grid 576 -> 147456
  if (i < CC*CC) {
    int o = i / CC, a = i % CC;
    int ct = o >> 4, l = o & 15, kc = a >> 5, q = (a & 31) >> 3, j = a & 7;
    int dst = ((ct*6 + kc)*64 + q*16 + l)*8 + j;
    wqF[dst] = f2b(wq[i]);
    wkF[dst] = f2b(wk[i]);
  }
  if (i < CC*CC*NH) {
    int o = i / (CC*NH), c2 = i % (CC*NH);
    int s = c2 / CC, cc = c2 % CC;
    int T = o >> 4, l = o & 15, kc = cc >> 5, q = (cc & 31) >> 3, j = cc & 7;
    int dst = (((s*12 + T)*6 + kc)*64 + q*16 + l)*8 + j;
    wpF[dst] = f2b(wp[i]);
  }
}

// ---------------- kernel 2: fused QK projection + scores ----------------
// grid 240 = (n, tc of 8 t's); 448 thr = 7 waves, wave w owns u-tile w.
// Per t: Q-proj (all heads) -> QT[u][o 0..191]; per head: K-proj -> KT[v][c' 0..47]; S += Q.K^T.
__global__ __launch_bounds__(448, 2) void k_scoresB(const float* __restrict__ xq,
                                                    const float* __restrict__ xkv,
                                                    const short* __restrict__ wqF,
                                                    const short* __restrict__ wkF,
                                                    const float* __restrict__ bq,
                                                    const float* __restrict__ bk,
                                                    float* __restrict__ part) {
  __shared__ short QT[112*200];   // [u][o], stride 200 (2-way banks, 16B rows)
  __shared__ short KT[112*56];    // [v][c'], per-head, stride 56
  const int n = blockIdx.x / 15, tc = blockIdx.x % 15;
  const int tid = threadIdx.x, w = tid >> 6, lane = tid & 63;
  const int q = lane >> 4, l15 = lane & 15;
  const int u = 16*w + l15, uc = (u < VV) ? u : (VV-1);

  float4v acc[NH][7];
  #pragma unroll
  for (int s = 0; s < NH; ++s)
    #pragma unroll
    for (int vt = 0; vt < 7; ++vt) acc[s][vt] = (float4v){0.f,0.f,0.f,0.f};

  const short8 z8 = {0,0,0,0,0,0,0,0};

  #pragma unroll 1
  for (int it = 0; it < 8; ++it) {
    const int t = tc*8 + it;
    // A-frags of x_q for this wave's u-tile: A[m=u][k=a]
    short8 xf[6];
    #pragma unroll
    for (int kc = 0; kc < 6; ++kc) {
      float f[8];
      #pragma unroll
      for (int j = 0; j < 8; ++j)
        f[j] = xq[(n*CC + 32*kc + 8*q + j)*(TT*VV) + t*VV + uc];
      S8U sv; sv.u[0]=pk2(f[0],f[1]); sv.u[1]=pk2(f[2],f[3]); sv.u[2]=pk2(f[4],f[5]); sv.u[3]=pk2(f[6],f[7]);
      xf[kc] = sv.s;
    }
    // Q-proj: D[u-rows][o-cols], all 12 o-tiles
    #pragma unroll
    for (int ct = 0; ct < 12; ++ct) {
      float4v d = (float4v){0.f,0.f,0.f,0.f};
      #pragma unroll
      for (int kc = 0; kc < 6; ++kc) {
        short8 wf = *(const short8*)&wqF[((ct*6 + kc)*64 + q*16 + l15)*8];
        d = MFMA16(xf[kc], wf, d);
      }
      float bb = bq[16*ct + l15];
      #pragma unroll
      for (int r = 0; r < 4; ++r)
        QT[(16*w + 4*q + r)*200 + 16*ct + l15] = b16t(d[r] + bb);
    }
    // A-frags of x_kv (positions act as v)
    short8 xg[6];
    #pragma unroll
    for (int kc = 0; kc < 6; ++kc) {
      float f[8];
      #pragma unroll
      for (int j = 0; j < 8; ++j)
        f[j] = xkv[(n*CC + 32*kc + 8*q + j)*(TT*VV) + t*VV + uc];
      S8U sv; sv.u[0]=pk2(f[0],f[1]); sv.u[1]=pk2(f[2],f[3]); sv.u[2]=pk2(f[4],f[5]); sv.u[3]=pk2(f[6],f[7]);
      xg[kc] = sv.s;
    }
    #pragma unroll 1
    for (int s = 0; s < NH; ++s) {
      // K-proj for head s: D[v-rows][c'-cols 0..47]
      #pragma unroll
      for (int ctk = 0; ctk < 3; ++ctk) {
        float4v d = (float4v){0.f,0.f,0.f,0.f};
        #pragma unroll
        for (int kc = 0; kc < 6; ++kc) {
          short8 wf = *(const short8*)&wkF[(((3*s + ctk)*6 + kc)*64 + q*16 + l15)*8];
          d = MFMA16(xg[kc], wf, d);
        }
        float bb = bk[48*s + 16*ctk + l15];
        #pragma unroll
        for (int r = 0; r < 4; ++r)
          KT[(16*w + 4*q + r)*56 + 16*ctk + l15] = b16t(d[r] + bb);
      }
      __syncthreads();
      // S[u][v] += Q[u][c'] K^T[c'][v], K=48 (c' 48..63 zeroed in regs)
      #pragma unroll
      for (int kcp = 0; kcp < 2; ++kcp) {
        short8 aQ = z8;
        if (kcp == 0 || q < 2)
          aQ = *(const short8*)&QT[(16*w + l15)*200 + 48*s + 32*kcp + 8*q];
        #pragma unroll
        for (int vt = 0; vt < 7; ++vt) {
          short8 bK = z8;
          if (kcp == 0 || q < 2)
            bK = *(const short8*)&KT[(16*vt + l15)*56 + 32*kcp + 8*q];
          acc[s][vt] = MFMA16(aQ, bK, acc[s][vt]);
        }
      }
      __syncthreads();
    }
  }
  // flush: part[n][tc][s][v][u112], D col=v, row=u
  #pragma unroll
  for (int s = 0; s < NH; ++s)
    #pragma unroll
    for (int vt = 0; vt < 7; ++vt) {
      int v = 16*vt + l15;
      if (v < VV)
        *(float4v*)&part[(((n*15 + tc)*NH + s)*VV + v)*112 + 16*w + 4*q] = acc[s][vt];
    }
}

// ---------------- kernel 3: reduce + tanh + alpha/ga -> attnT bf16 [n][s][v112][u128] ----------------
__global__ __launch_bounds__(256) void k_reduce(const float* __restrict__ part,
                                                const float* __restrict__ alphas,
                                                const float* __restrict__ ga,
                                                short* __restrict__ attnT) {
  int bid = blockIdx.x;                 // 16*4*56 = 3584
  int n = bid / 224, rem = bid % 224, s = rem / 56, vc = rem % 56;
  int v = vc*2 + (threadIdx.x >> 7), uu = threadIdx.x & 127;
  float val = 0.f;
  if (v < VV && uu < VV) {
    float sum = 0.f;
    for (int tcc = 0; tcc < 15; ++tcc)
      sum += part[(((n*15 + tcc)*NH + s)*VV + v)*112 + uu];
    val = tanhf(sum * (1.f/5760.f)) * alphas[s] + ga[uu*VV + v];
  }
  attnT[((n*NH + s)*112 + v)*128 + uu] = f2b(val);
}

// ---------------- kernel 4: fused value-proj + attn-apply + out-proj ----------------
// grid 1920 = (n,t); 256 thr = 4 waves; wave w owns o-tiles {w, w+4, w+8}. ONE barrier.
__global__ __launch_bounds__(256, 2) void k_outB(const float* __restrict__ xkv,
                                                 const short* __restrict__ wpF,
                                                 const short* __restrict__ attnT,
                                                 const float* __restrict__ bp,
                                                 float* __restrict__ out) {
  __shared__ short XT[112*200];      // x_kv^T [u][c] bf16, 44800 B
  __shared__ short MsW[4*16*136];    // per-wave Ms strip [o16][u136], 17408 B
  const int n = blockIdx.x / TT, t = blockIdx.x % TT;
  const int tid = threadIdx.x, w = tid >> 6, lane = tid & 63;
  const int q = lane >> 4, l15 = lane & 15;

  for (int i = tid; i < 4*16*136/2; i += 256) ((int*)MsW)[i] = 0;  // zero pads once

  // stage XT: thread reads 4 c at fixed u, packs, b64 write
  for (int it = 0; it < 21; ++it) {
    int idx = it*256 + tid;            // 112*48 = 5376
    int u = idx % 112, cq = idx / 112;
    int uc = (u < VV) ? u : (VV-1);
    const float* px = &xkv[(n*CC + 4*cq)*(TT*VV) + t*VV + uc];
    float f0 = px[0], f1 = px[TT*VV], f2 = px[2*TT*VV], f3 = px[3*TT*VV];
    int2v pr; pr.x = (int)pk2(f0, f1); pr.y = (int)pk2(f2, f3);
    *(int2v*)&XT[u*200 + 4*cq] = pr;
  }
  __syncthreads();

  float4v accO[3][7];
  #pragma unroll
  for (int i = 0; i < 3; ++i)
    #pragma unroll
    for (int vt = 0; vt < 7; ++vt) accO[i][vt] = (float4v){0.f,0.f,0.f,0.f};

  #pragma unroll 1
  for (int s = 0; s < NH; ++s) {
    // B1: Ms[o][u] = sum_c wp[o][s*192+c] * x[c][u];  A=XT[m=u], B=wpF[col=o] (wave-private o)
    float4v acc1[3][7];
    #pragma unroll
    for (int i = 0; i < 3; ++i)
      #pragma unroll
      for (int ut = 0; ut < 7; ++ut) acc1[i][ut] = (float4v){0.f,0.f,0.f,0.f};
    #pragma unroll
    for (int kc = 0; kc < 6; ++kc) {
      short8 xa[7];
      #pragma unroll
      for (int ut = 0; ut < 7; ++ut)
        xa[ut] = *(const short8*)&XT[(16*ut + l15)*200 + 32*kc + 8*q];
      #pragma unroll
      for (int i = 0; i < 3; ++i) {
        short8 wf = *(const short8*)&wpF[(((s*12 + (w + 4*i))*6 + kc)*64 + q*16 + l15)*8];
        #pragma unroll
        for (int ut = 0; ut < 7; ++ut)
          acc1[i][ut] = MFMA16(xa[ut], wf, acc1[i][ut]);
      }
    }
    // per o-tile: pack Ms to private LDS strip, then B2 accumulate (same-wave, no barrier)
    #pragma unroll
    for (int i = 0; i < 3; ++i) {
      #pragma unroll
      for (int ut = 0; ut < 7; ++ut) {
        float4v d = acc1[i][ut];
        int2v pr; pr.x = (int)pk2(d[0], d[1]); pr.y = (int)pk2(d[2], d[3]);
        *(int2v*)&MsW[(w*16 + l15)*136 + 16*ut + 4*q] = pr;   // D: col=o=l15, row=u
      }
      #pragma unroll
      for (int kc = 0; kc < 4; ++kc) {
        short8 mb = *(const short8*)&MsW[(w*16 + l15)*136 + 32*kc + 8*q];  // B[k=u][col=o]
        #pragma unroll
        for (int vt = 0; vt < 7; ++vt) {
          short8 av = *(const short8*)&attnT[((n*NH + s)*112 + 16*vt + l15)*128 + 32*kc + 8*q];
          accO[i][vt] = MFMA16(av, mb, accO[i][vt]);          // D[m=v][col=o]
        }
      }
    }
  }
  // epilogue: + bp, v-contiguous float4 stores
  #pragma unroll
  for (int i = 0; i < 3; ++i) {
    int o = 16*(w + 4*i) + l15;
    float b = bp[o];
    #pragma unroll
    for (int vt = 0; vt < 7; ++vt) {
      int v0 = 16*vt + 4*q;
      if (v0 < VV) {
        float4v r = accO[i][vt];
        r[0] += b; r[1] += b; r[2] += b; r[3] += b;
        *(float4v*)&out[((n*CC + o)*TT + t)*VV + v0] = r;
      }
    }
  }
}

extern "C" void kernel_launch(void* const* d_in, const int* in_sizes, int n_in,
                              void* d_out, int out_size, void* d_ws, size_t ws_size,
                              hipStream_t stream) {
  const float* xq     = (const float*)d_in[0];
  const float* xkv    = (const float*)d_in[1];
  const float* wq     = (const float*)d_in[2];
  const float* bq     = (const float*)d_in[3];
  const float* wk     = (const float*)d_in[4];
  const float* bk     = (const float*)d_in[5];
  const float* wp     = (const float*)d_in[6];
  const float* bp     = (const float*)d_in[7];
  const float* alphas = (const float*)d_in[8];
  const float* ga     = (const float*)d_in[9];
  float* out = (float*)d_out;
  char*  ws  = (char*)d_ws;

  // ws: wqF 0..73728 | wkF ..147456 | wpF ..442368 | attnT ..2277376 | part ..45285376
  short* wqF   = (short*)(ws);
  short* wkF   = (short*)(ws + 73728);
  short* wpF   = (short*)(ws + 147456);
  short* attnT = (short*)(ws + 442368);
  float* part  = (float*)(ws + 2277376);

  hipLaunchKernelGGL(k_conv,    dim3(576),  dim3(256), 0, stream, wq, wk, wp, wqF, wkF, wpF);
  hipLaunchKernelGGL(k_scoresB, dim3(240),  dim3(448), 0, stream, xq, xkv, wqF, wkF, bq, bk, part);
  hipLaunchKernelGGL(k_reduce,  dim3(3584), dim3(256), 0, stream, part, alphas, ga, attnT);
  hipLaunchKernelGGL(k_outB,    dim3(1920), dim3(256), 0, stream, xkv, wpF, attnT, bp, out);
}